// Round 3
// baseline (776.119 us; speedup 1.0000x reference)
//
#include <hip/hip_runtime.h>
#include <math.h>

#define BB 16
#define CC 256
#define NN 9216        // 96*96
#define NCHUNK 72      // k_kv chunks per image (4 tiles of 32 each = 128 pos)
#define EPSV 1e-5f
#define KSTR 36        // k_kv LDS row stride (32 data + 4 pad, keeps 16B align)
#define OSTR 32        // k_out LDS row stride

// ---- workspace layout (float offsets) ----
#define WS_SUMS  0                          // [B][C][2]  per-channel sum, sumsq
#define WS_AB    (WS_SUMS + BB*CC*2)        // [B][C][2]  affine a, b  (xn = a*x+b)
#define WS_GATE  (WS_AB + BB*CC*2)          // [B]
#define WS_MPART (WS_GATE + BB)             // [B][72][1024]
#define WS_ZPART (WS_MPART + BB*NCHUNK*1024)// [B][72][64]
#define WS_MF    (WS_ZPART + BB*NCHUNK*64)  // [B][1024]
#define WS_ZF    (WS_MF + BB*1024)          // [B][64]
// total ≈ 1,287,184 floats ≈ 5.15 MB (same as round 1 — known to fit)

#define AXPY4(acc, s, v) do { (acc).x += (s)*(v).x; (acc).y += (s)*(v).y; \
                              (acc).z += (s)*(v).z; (acc).w += (s)*(v).w; } while(0)

__device__ __forceinline__ float elup1(float v) { return v > 0.f ? v + 1.f : expf(v); }

// ---------------- kernel 1: per-channel sums ----------------
__global__ __launch_bounds__(256) void k_stats(const float* __restrict__ x,
                                               float* __restrict__ ws) {
  const int bc = blockIdx.x;                     // b*C + c
  const float4* p4 = (const float4*)(x + (size_t)bc * NN);
  float s = 0.f, s2 = 0.f;
  for (int i = threadIdx.x; i < NN/4; i += 256) {
    float4 v = p4[i];
    s  += v.x + v.y + v.z + v.w;
    s2 += v.x*v.x + v.y*v.y + v.z*v.z + v.w*v.w;
  }
  for (int off = 32; off > 0; off >>= 1) {
    s  += __shfl_down(s,  off);
    s2 += __shfl_down(s2, off);
  }
  __shared__ float rs[4], rs2[4];
  const int wid = threadIdx.x >> 6, lane = threadIdx.x & 63;
  if (lane == 0) { rs[wid] = s; rs2[wid] = s2; }
  __syncthreads();
  if (threadIdx.x == 0) {
    ws[WS_SUMS + bc*2]     = rs[0]+rs[1]+rs[2]+rs[3];
    ws[WS_SUMS + bc*2 + 1] = rs2[0]+rs2[1]+rs2[2]+rs2[3];
  }
}

// ---------------- kernel 2: group stats -> affine, pooled, gate ----------------
__global__ __launch_bounds__(256) void k_prep(const float* __restrict__ norm_w,
                                              const float* __restrict__ norm_b,
                                              const float* __restrict__ Wg1,
                                              const float* __restrict__ bg1,
                                              const float* __restrict__ Wg2,
                                              const float* __restrict__ bg2,
                                              float* __restrict__ ws,
                                              float* __restrict__ out) {
  const int b = blockIdx.x, c = threadIdx.x;     // 256 threads == C
  const float s  = ws[WS_SUMS + (b*CC+c)*2];
  const float s2 = ws[WS_SUMS + (b*CC+c)*2 + 1];
  float gs = s, gs2 = s2;                        // 32 consecutive channels/group
  for (int off = 1; off < 32; off <<= 1) {
    gs  += __shfl_xor(gs,  off);
    gs2 += __shfl_xor(gs2, off);
  }
  const float inv = 1.0f / (32.0f * (float)NN);
  const float mu  = gs * inv;
  const float var = gs2 * inv - mu*mu;
  const float rstd = rsqrtf(var + EPSV);
  const float w = norm_w[c], nb = norm_b[c];
  const float a   = w * rstd;
  const float bbv = nb - w * mu * rstd;
  ws[WS_AB + (b*CC+c)*2]     = a;
  ws[WS_AB + (b*CC+c)*2 + 1] = bbv;

  __shared__ float pooled[CC];
  __shared__ float g1[64];
  pooled[c] = fmaf(a, s * (1.0f/(float)NN), bbv);
  __syncthreads();
  if (c < 64) {
    float acc = bg1[c];
    const float* wr = Wg1 + c*CC;
    for (int i = 0; i < CC; ++i) acc = fmaf(wr[i], pooled[i], acc);
    g1[c] = 0.5f * acc * (1.0f + erff(acc * 0.70710678118654752f));  // exact GELU
  }
  __syncthreads();
  if (c == 0) {
    float acc = bg2[0];
    for (int o = 0; o < 64; ++o) acc = fmaf(Wg2[o], g1[o], acc);
    const float gate = 1.0f / (1.0f + expf(-acc));
    ws[WS_GATE + b] = gate;
    out[(size_t)BB*CC*NN + b] = gate;            // gate output (tuple tail)
  }
}

// ---------------- kernel 3: k,v projection + partial M,Z ----------------
// 32-position tiles, 4 per block. LDS ~38.9KB -> 4 blocks/CU.
__global__ __launch_bounds__(256, 4) void k_kv(const float* __restrict__ x,
                                               const float* __restrict__ Wk,
                                               const float* __restrict__ Wv,
                                               float* __restrict__ ws) {
  const int chunk = blockIdx.x;                  // 0..71 (128 positions each)
  const int b = blockIdx.y;
  const int tid = threadIdx.x;
  __shared__ float lds[CC*KSTR];                 // xn tile; then phi_k rows 0..63, v rows 64..127
  __shared__ float alds[CC], blds[CC];
  alds[tid] = ws[WS_AB + (b*CC+tid)*2];
  blds[tid] = ws[WS_AB + (b*CC+tid)*2 + 1];

  const int cc0 = tid >> 3, t8 = tid & 7;        // staging: 8 rows x float4
  const int to = tid >> 3, tt = tid & 7;         // gemm: 4 o x 4 t per thread
  const int obase = to*4;
  const float4* Wm4 = (obase < 64) ? (const float4*)Wk : (const float4*)Wv;
  const int orow = (obase < 64) ? obase : (obase - 64);

  const int mh = tid >> 6, md = (tid >> 2) & 15, me0 = (tid & 3)*4;
  float macc0=0.f, macc1=0.f, macc2=0.f, macc3=0.f, zacc=0.f;

  for (int tile = 0; tile < 4; ++tile) {
    const int n0 = chunk*128 + tile*32;
    __syncthreads();                             // prev M-partial reads done
    #pragma unroll
    for (int ci = 0; ci < 8; ++ci) {
      const int c = ci*32 + cc0;
      float4 xv = *(const float4*)(x + (size_t)(b*CC + c)*NN + n0 + t8*4);
      const float a = alds[c], bbv = blds[c];
      float4 r;
      r.x = fmaf(a, xv.x, bbv); r.y = fmaf(a, xv.y, bbv);
      r.z = fmaf(a, xv.z, bbv); r.w = fmaf(a, xv.w, bbv);
      *(float4*)&lds[c*KSTR + t8*4] = r;
    }
    __syncthreads();

    // GEMM: [128 o] x [32 t]; thread: 4 o x 4 t
    float4 acc[4];
    #pragma unroll
    for (int i = 0; i < 4; ++i) acc[i] = make_float4(0.f,0.f,0.f,0.f);
    for (int c4 = 0; c4 < 64; ++c4) {
      const float4 xv0 = *(const float4*)&lds[(c4*4+0)*KSTR + tt*4];
      const float4 xv1 = *(const float4*)&lds[(c4*4+1)*KSTR + tt*4];
      const float4 xv2 = *(const float4*)&lds[(c4*4+2)*KSTR + tt*4];
      const float4 xv3 = *(const float4*)&lds[(c4*4+3)*KSTR + tt*4];
      #pragma unroll
      for (int i = 0; i < 4; ++i) {
        const float4 wv = Wm4[(orow+i)*64 + c4];
        AXPY4(acc[i], wv.x, xv0);
        AXPY4(acc[i], wv.y, xv1);
        AXPY4(acc[i], wv.z, xv2);
        AXPY4(acc[i], wv.w, xv3);
      }
    }
    __syncthreads();                             // all xn reads done
    if (obase < 64) {                            // wave-uniform
      #pragma unroll
      for (int i = 0; i < 4; ++i) {
        float4 p;
        p.x = elup1(acc[i].x); p.y = elup1(acc[i].y);
        p.z = elup1(acc[i].z); p.w = elup1(acc[i].w);
        *(float4*)&lds[(obase+i)*KSTR + tt*4] = p;     // phi_k rows 0..63
      }
    } else {
      #pragma unroll
      for (int i = 0; i < 4; ++i)
        *(float4*)&lds[(obase+i)*KSTR + tt*4] = acc[i]; // v rows 64..127
    }
    __syncthreads();

    // partial M[h][d][e]; 4 entries/thread; stride 36 -> rows rotate bank quads
    {
      const float* phrow = &lds[(mh*16+md)*KSTR];
      const float* v0 = &lds[(64 + mh*16 + me0 + 0)*KSTR];
      const float* v1 = &lds[(64 + mh*16 + me0 + 1)*KSTR];
      const float* v2 = &lds[(64 + mh*16 + me0 + 2)*KSTR];
      const float* v3 = &lds[(64 + mh*16 + me0 + 3)*KSTR];
      #pragma unroll
      for (int q = 0; q < 8; ++q) {
        const float4 ph = *(const float4*)&phrow[q*4];
        const float4 a0 = *(const float4*)&v0[q*4];
        const float4 a1 = *(const float4*)&v1[q*4];
        const float4 a2 = *(const float4*)&v2[q*4];
        const float4 a3 = *(const float4*)&v3[q*4];
        macc0 += ph.x*a0.x + ph.y*a0.y + ph.z*a0.z + ph.w*a0.w;
        macc1 += ph.x*a1.x + ph.y*a1.y + ph.z*a1.z + ph.w*a1.w;
        macc2 += ph.x*a2.x + ph.y*a2.y + ph.z*a2.z + ph.w*a2.w;
        macc3 += ph.x*a3.x + ph.y*a3.y + ph.z*a3.z + ph.w*a3.w;
      }
      if (tid < 64) {                            // Z[h][d] partial (phi_k row tid)
        const float* pr = &lds[tid*KSTR];
        #pragma unroll
        for (int q = 0; q < 8; ++q) {
          const float4 p = *(const float4*)&pr[q*4];
          zacc += p.x + p.y + p.z + p.w;
        }
      }
    }
  }
  {
    float* mp = ws + WS_MPART + ((size_t)b*NCHUNK + chunk)*1024 + tid*4;
    mp[0] = macc0; mp[1] = macc1; mp[2] = macc2; mp[3] = macc3;
    if (tid < 64) ws[WS_ZPART + ((size_t)b*NCHUNK + chunk)*64 + tid] = zacc;
  }
}

// ---------------- kernel 4: reduce partials, add M0/Z0 ----------------
__global__ __launch_bounds__(256) void k_reduce(const float* __restrict__ M0,
                                                const float* __restrict__ Z0,
                                                float* __restrict__ ws) {
  const int b = blockIdx.x, tid = threadIdx.x;
  const int idx0 = tid*4;
  float4 s = *(const float4*)(M0 + idx0);
  for (int ch = 0; ch < NCHUNK; ++ch) {
    const float4 p = *(const float4*)&ws[WS_MPART + ((size_t)b*NCHUNK + ch)*1024 + idx0];
    s.x += p.x; s.y += p.y; s.z += p.z; s.w += p.w;
  }
  *(float4*)&ws[WS_MF + b*1024 + idx0] = s;
  if (tid < 64) {
    float z = Z0[tid];
    for (int ch = 0; ch < NCHUNK; ++ch)
      z += ws[WS_ZPART + ((size_t)b*NCHUNK + ch)*64 + tid];
    ws[WS_ZF + b*64 + tid] = z;
  }
}

// ---------------- kernel 5: q proj + retrieval + out conv + residual ----------------
// 32-position tiles. LDS ~39.2KB -> 4 blocks/CU.
__global__ __launch_bounds__(256, 4) void k_out(const float* __restrict__ x,
                                                const float* __restrict__ Wq,
                                                const float* __restrict__ Wout,
                                                const float* __restrict__ bout,
                                                const float* __restrict__ ws,
                                                float* __restrict__ out) {
  const int tile = blockIdx.x;                   // 0..287
  const int b = blockIdx.y;
  const int tid = threadIdx.x;
  const int n0 = tile*32;
  __shared__ float lds[CC*OSTR];                 // xn; then phiq rows 0..63, y rows 64..127
  __shared__ float Ml[1024];
  __shared__ float Zl[64];
  __shared__ float alds[CC], blds[CC];
  alds[tid] = ws[WS_AB + (b*CC+tid)*2];
  blds[tid] = ws[WS_AB + (b*CC+tid)*2 + 1];
  {
    const float* mf = ws + WS_MF + b*1024;
    #pragma unroll
    for (int j = 0; j < 4; ++j) Ml[tid*4+j] = mf[tid*4+j];
    if (tid < 64) Zl[tid] = ws[WS_ZF + b*64 + tid];
  }
  const float gate = ws[WS_GATE + b];
  __syncthreads();

  const int cc0 = tid >> 3, t8 = tid & 7;
  #pragma unroll
  for (int ci = 0; ci < 8; ++ci) {
    const int c = ci*32 + cc0;
    float4 xv = *(const float4*)(x + (size_t)(b*CC + c)*NN + n0 + t8*4);
    const float a = alds[c], bbv = blds[c];
    float4 r;
    r.x = fmaf(a, xv.x, bbv); r.y = fmaf(a, xv.y, bbv);
    r.z = fmaf(a, xv.z, bbv); r.w = fmaf(a, xv.w, bbv);
    *(float4*)&lds[c*OSTR + t8*4] = r;
  }
  __syncthreads();

  // q GEMM: 64 o x 32 t; thread: 2 o x 4 t
  const int to = tid >> 3, tt = tid & 7;
  const int o0 = to*2;
  float4 q0 = make_float4(0.f,0.f,0.f,0.f), q1 = q0;
  const float4* Wq4 = (const float4*)Wq;
  for (int c4 = 0; c4 < 64; ++c4) {
    const float4 xv0 = *(const float4*)&lds[(c4*4+0)*OSTR + tt*4];
    const float4 xv1 = *(const float4*)&lds[(c4*4+1)*OSTR + tt*4];
    const float4 xv2 = *(const float4*)&lds[(c4*4+2)*OSTR + tt*4];
    const float4 xv3 = *(const float4*)&lds[(c4*4+3)*OSTR + tt*4];
    const float4 w0 = Wq4[(o0+0)*64 + c4];
    const float4 w1 = Wq4[(o0+1)*64 + c4];
    AXPY4(q0, w0.x, xv0); AXPY4(q0, w0.y, xv1); AXPY4(q0, w0.z, xv2); AXPY4(q0, w0.w, xv3);
    AXPY4(q1, w1.x, xv0); AXPY4(q1, w1.y, xv1); AXPY4(q1, w1.z, xv2); AXPY4(q1, w1.w, xv3);
  }
  q0.x=elup1(q0.x); q0.y=elup1(q0.y); q0.z=elup1(q0.z); q0.w=elup1(q0.w);
  q1.x=elup1(q1.x); q1.y=elup1(q1.y); q1.z=elup1(q1.z); q1.w=elup1(q1.w);
  __syncthreads();                               // xn fully consumed
  *(float4*)&lds[(o0+0)*OSTR + tt*4] = q0;       // phiq rows 0..63
  *(float4*)&lds[(o0+1)*OSTR + tt*4] = q1;
  __syncthreads();

  // y[e][t] = (sum_d M[d][e] phiq[d][t]) / max(sum_d Z[d] phiq[d][t], 1e-4)
  {
    const int e0g = to*2;
    const int h = e0g >> 4;
    const int el0 = e0g & 15;
    float4 n0v = make_float4(0.f,0.f,0.f,0.f), n1v = n0v, den = n0v;
    #pragma unroll
    for (int d = 0; d < 16; ++d) {
      const float4 ph = *(const float4*)&lds[(h*16+d)*OSTR + tt*4];
      AXPY4(den, Zl[h*16+d], ph);
      const float* mrow = &Ml[h*256 + d*16 + el0];
      AXPY4(n0v, mrow[0], ph);
      AXPY4(n1v, mrow[1], ph);
    }
    den.x = fmaxf(den.x, 1e-4f); den.y = fmaxf(den.y, 1e-4f);
    den.z = fmaxf(den.z, 1e-4f); den.w = fmaxf(den.w, 1e-4f);
    float4 y0, y1;
    y0.x = n0v.x/den.x; y0.y = n0v.y/den.y; y0.z = n0v.z/den.z; y0.w = n0v.w/den.w;
    y1.x = n1v.x/den.x; y1.y = n1v.y/den.y; y1.z = n1v.z/den.z; y1.w = n1v.w/den.w;
    *(float4*)&lds[(64 + e0g + 0)*OSTR + tt*4] = y0;   // y rows 64..127
    *(float4*)&lds[(64 + e0g + 1)*OSTR + tt*4] = y1;
  }
  __syncthreads();

  // out conv 256 c x 32 t; thread: 4 c x 8 t
  const int cg = tid >> 2, tg = tid & 3;
  const int c0 = cg*4, t0 = tg*8;
  float4 oa[4][2];
  #pragma unroll
  for (int i = 0; i < 4; ++i) { oa[i][0] = make_float4(0.f,0.f,0.f,0.f); oa[i][1] = oa[i][0]; }
  const float4* Wo4 = (const float4*)Wout;
  #pragma unroll 4
  for (int m4 = 0; m4 < 16; ++m4) {
    const float4 wv0 = Wo4[(c0+0)*16 + m4];
    const float4 wv1 = Wo4[(c0+1)*16 + m4];
    const float4 wv2 = Wo4[(c0+2)*16 + m4];
    const float4 wv3 = Wo4[(c0+3)*16 + m4];
#define OUTSTEP(WC, MM) { \
    const float* yr = &lds[(64 + m4*4 + MM)*OSTR + t0]; \
    const float4 ya = *(const float4*)&yr[0];  \
    const float4 yb = *(const float4*)&yr[4];  \
    AXPY4(oa[0][0], wv0.WC, ya); AXPY4(oa[0][1], wv0.WC, yb); \
    AXPY4(oa[1][0], wv1.WC, ya); AXPY4(oa[1][1], wv1.WC, yb); \
    AXPY4(oa[2][0], wv2.WC, ya); AXPY4(oa[2][1], wv2.WC, yb); \
    AXPY4(oa[3][0], wv3.WC, ya); AXPY4(oa[3][1], wv3.WC, yb); }
    OUTSTEP(x, 0)
    OUTSTEP(y, 1)
    OUTSTEP(z, 2)
    OUTSTEP(w, 3)
#undef OUTSTEP
  }
  // epilogue: out = x + gate*(conv + bout)
  #pragma unroll
  for (int i = 0; i < 4; ++i) {
    const int c = c0 + i;
    const float bo = bout[c];
    const float* xb = x   + (size_t)(b*CC + c)*NN + n0 + t0;
    float*       ob = out + (size_t)(b*CC + c)*NN + n0 + t0;
    #pragma unroll
    for (int q = 0; q < 2; ++q) {
      const float4 xg = *(const float4*)(xb + q*4);
      const float4 v = oa[i][q];
      float4 r;
      r.x = fmaf(gate, v.x + bo, xg.x);
      r.y = fmaf(gate, v.y + bo, xg.y);
      r.z = fmaf(gate, v.z + bo, xg.z);
      r.w = fmaf(gate, v.w + bo, xg.w);
      *(float4*)(ob + q*4) = r;
    }
  }
}

extern "C" void kernel_launch(void* const* d_in, const int* in_sizes, int n_in,
                              void* d_out, int out_size, void* d_ws, size_t ws_size,
                              hipStream_t stream) {
  (void)in_sizes; (void)n_in; (void)out_size; (void)ws_size;
  const float* x      = (const float*)d_in[0];
  const float* norm_w = (const float*)d_in[1];
  const float* norm_b = (const float*)d_in[2];
  const float* Wk     = (const float*)d_in[3];
  const float* Wv     = (const float*)d_in[4];
  const float* Wq     = (const float*)d_in[5];
  const float* Wout   = (const float*)d_in[6];
  const float* bout   = (const float*)d_in[7];
  const float* M0     = (const float*)d_in[8];
  const float* Z0     = (const float*)d_in[9];
  const float* Wg1    = (const float*)d_in[10];
  const float* bg1    = (const float*)d_in[11];
  const float* Wg2    = (const float*)d_in[12];
  const float* bg2    = (const float*)d_in[13];
  float* out = (float*)d_out;
  float* ws  = (float*)d_ws;

  hipLaunchKernelGGL(k_stats,  dim3(BB*CC),      dim3(256), 0, stream, x, ws);
  hipLaunchKernelGGL(k_prep,   dim3(BB),         dim3(256), 0, stream,
                     norm_w, norm_b, Wg1, bg1, Wg2, bg2, ws, out);
  hipLaunchKernelGGL(k_kv,     dim3(NCHUNK, BB), dim3(256), 0, stream, x, Wk, Wv, ws);
  hipLaunchKernelGGL(k_reduce, dim3(BB),         dim3(256), 0, stream, M0, Z0, ws);
  hipLaunchKernelGGL(k_out,    dim3(288, BB),    dim3(256), 0, stream,
                     x, Wq, Wout, bout, ws, out);
}

// Round 5
// 448.994 us; speedup vs baseline: 1.7286x; 1.7286x over previous
//
#include <hip/hip_runtime.h>
#include <math.h>

#define BB 16
#define CC 256
#define NN 9216        // 96*96
#define NCH 36         // chunks per image; each block does 4 tiles of 64 = 256 pos
#define EPSV 1e-5f
#define XSTR 264       // xnt row stride (bf16): 256 data + 8 pad; 528B = 33*16 ✓ b128-aligned
#define PSTR 72        // PHI/V row stride (bf16): 144B = 9*16 ✓
#define YSTR 72        // y row stride (bf16)

typedef short bf16x8 __attribute__((ext_vector_type(8)));
typedef float f32x4  __attribute__((ext_vector_type(4)));
#define MFMA16(a,b,c) __builtin_amdgcn_mfma_f32_16x16x32_bf16(a,b,c,0,0,0)

// ---- workspace layout (float offsets) ----
#define WS_SUMS  0                           // [B][C][2]
#define WS_AB    (WS_SUMS + BB*CC*2)         // [B][C][2]
#define WS_GATE  (WS_AB + BB*CC*2)           // [B]
#define WS_MPART (WS_GATE + BB)              // [B][36][1024]
#define WS_ZPART (WS_MPART + BB*NCH*1024)    // [B][36][64]
#define WS_MF    (WS_ZPART + BB*NCH*64)      // [B][1024]
#define WS_ZF    (WS_MF + BB*1024)           // [B][64]
// total ≈ 660k floats ≈ 2.6 MB (round-1 used 5.15 MB successfully)

__device__ __forceinline__ float elup1(float v) { return v > 0.f ? v + 1.f : expf(v); }

__device__ __forceinline__ short f2bf(float f) {       // RNE fp32 -> bf16 bits
  unsigned u = __float_as_uint(f);
  u += 0x7fffu + ((u >> 16) & 1u);
  return (short)(u >> 16);
}
__device__ __forceinline__ float bf2f(short s) {
  return __uint_as_float(((unsigned)(unsigned short)s) << 16);
}
__device__ __forceinline__ bf16x8 packAB(float4 lo, float4 hi) {
  bf16x8 r;
  r[0]=f2bf(lo.x); r[1]=f2bf(lo.y); r[2]=f2bf(lo.z); r[3]=f2bf(lo.w);
  r[4]=f2bf(hi.x); r[5]=f2bf(hi.y); r[6]=f2bf(hi.z); r[7]=f2bf(hi.w);
  return r;
}

// stage one 64-pos tile: xn = a*x+b, bf16, transposed [n][c] into xnt (stride XSTR)
__device__ __forceinline__ void stage_tile(const float* __restrict__ xb,
    const float* __restrict__ alds, const float* __restrict__ blds,
    short* __restrict__ xnt, int tid, int n0) {
  const int c0  = (tid >> 2) * 4;        // 4 channels per thread
  const int nn0 = (tid & 3) * 16;        // 16 positions per thread
  const float a0=alds[c0+0], a1=alds[c0+1], a2=alds[c0+2], a3=alds[c0+3];
  const float e0=blds[c0+0], e1=blds[c0+1], e2=blds[c0+2], e3=blds[c0+3];
  const float* r0 = xb + (size_t)(c0+0)*NN + n0 + nn0;
  const float* r1 = xb + (size_t)(c0+1)*NN + n0 + nn0;
  const float* r2 = xb + (size_t)(c0+2)*NN + n0 + nn0;
  const float* r3 = xb + (size_t)(c0+3)*NN + n0 + nn0;
  #pragma unroll
  for (int i = 0; i < 4; ++i) {
    float4 v0 = *(const float4*)(r0 + i*4);
    float4 v1 = *(const float4*)(r1 + i*4);
    float4 v2 = *(const float4*)(r2 + i*4);
    float4 v3 = *(const float4*)(r3 + i*4);
    float q0[4] = {v0.x,v0.y,v0.z,v0.w};
    float q1[4] = {v1.x,v1.y,v1.z,v1.w};
    float q2[4] = {v2.x,v2.y,v2.z,v2.w};
    float q3[4] = {v3.x,v3.y,v3.z,v3.w};
    #pragma unroll
    for (int j = 0; j < 4; ++j) {
      short4 s;
      s.x = f2bf(fmaf(a0, q0[j], e0));
      s.y = f2bf(fmaf(a1, q1[j], e1));
      s.z = f2bf(fmaf(a2, q2[j], e2));
      s.w = f2bf(fmaf(a3, q3[j], e3));
      *(short4*)&xnt[(nn0 + i*4 + j)*XSTR + c0] = s;   // 8B-aligned b64 write
    }
  }
}

// ---------------- kernel 1: per-channel sums ----------------
__global__ __launch_bounds__(256) void k_stats(const float* __restrict__ x,
                                               float* __restrict__ ws) {
  const int bc = blockIdx.x;
  const float4* p4 = (const float4*)(x + (size_t)bc * NN);
  float s = 0.f, s2 = 0.f;
  for (int i = threadIdx.x; i < NN/4; i += 256) {
    float4 v = p4[i];
    s  += v.x + v.y + v.z + v.w;
    s2 += v.x*v.x + v.y*v.y + v.z*v.z + v.w*v.w;
  }
  for (int off = 32; off > 0; off >>= 1) {
    s  += __shfl_down(s,  off);
    s2 += __shfl_down(s2, off);
  }
  __shared__ float rs[4], rs2[4];
  const int wid = threadIdx.x >> 6, lane = threadIdx.x & 63;
  if (lane == 0) { rs[wid] = s; rs2[wid] = s2; }
  __syncthreads();
  if (threadIdx.x == 0) {
    ws[WS_SUMS + bc*2]     = rs[0]+rs[1]+rs[2]+rs[3];
    ws[WS_SUMS + bc*2 + 1] = rs2[0]+rs2[1]+rs2[2]+rs2[3];
  }
}

// ---------------- kernel 2: group stats -> affine, pooled, gate ----------------
__global__ __launch_bounds__(256) void k_prep(const float* __restrict__ norm_w,
                                              const float* __restrict__ norm_b,
                                              const float* __restrict__ Wg1,
                                              const float* __restrict__ bg1,
                                              const float* __restrict__ Wg2,
                                              const float* __restrict__ bg2,
                                              float* __restrict__ ws,
                                              float* __restrict__ out) {
  const int b = blockIdx.x, c = threadIdx.x;
  const float s  = ws[WS_SUMS + (b*CC+c)*2];
  const float s2 = ws[WS_SUMS + (b*CC+c)*2 + 1];
  float gs = s, gs2 = s2;
  for (int off = 1; off < 32; off <<= 1) {
    gs  += __shfl_xor(gs,  off);
    gs2 += __shfl_xor(gs2, off);
  }
  const float inv = 1.0f / (32.0f * (float)NN);
  const float mu  = gs * inv;
  const float var = gs2 * inv - mu*mu;
  const float rstd = rsqrtf(var + EPSV);
  const float w = norm_w[c], nb = norm_b[c];
  const float a   = w * rstd;
  const float bbv = nb - w * mu * rstd;
  ws[WS_AB + (b*CC+c)*2]     = a;
  ws[WS_AB + (b*CC+c)*2 + 1] = bbv;

  __shared__ float pooled[CC];
  __shared__ float g1[64];
  pooled[c] = fmaf(a, s * (1.0f/(float)NN), bbv);
  __syncthreads();
  if (c < 64) {
    float acc = bg1[c];
    const float* wr = Wg1 + c*CC;
    for (int i = 0; i < CC; ++i) acc = fmaf(wr[i], pooled[i], acc);
    g1[c] = 0.5f * acc * (1.0f + erff(acc * 0.70710678118654752f));
  }
  __syncthreads();
  if (c == 0) {
    float acc = bg2[0];
    for (int o = 0; o < 64; ++o) acc = fmaf(Wg2[o], g1[o], acc);
    const float gate = 1.0f / (1.0f + expf(-acc));
    ws[WS_GATE + b] = gate;
    out[(size_t)BB*CC*NN + b] = gate;
  }
}

// ---------------- kernel 3: k,v projection + partial M,Z (MFMA) ----------------
__global__ __launch_bounds__(256) void k_kv(const float* __restrict__ x,
                                            const float* __restrict__ Wk,
                                            const float* __restrict__ Wv,
                                            float* __restrict__ ws) {
  const int chunk = blockIdx.x, b = blockIdx.y;
  const int tid = threadIdx.x;
  const int w = tid >> 6, l = tid & 63, lr = l & 15, lg = l >> 4;
  __shared__ __align__(16) short xnt[64*XSTR];   // 33.8 KB; reused for PHI+V
  __shared__ float alds[CC], blds[CC];
  alds[tid] = ws[WS_AB + (b*CC+tid)*2];
  blds[tid] = ws[WS_AB + (b*CC+tid)*2 + 1];

  // A-fragments in registers: waves 0,1 -> Wk rows; waves 2,3 -> Wv rows
  const float* Wm = (w < 2) ? Wk : Wv;
  const int obase = (w & 1) * 32;
  bf16x8 afrag[2][8];
  #pragma unroll
  for (int ot = 0; ot < 2; ++ot) {
    const float* wr = Wm + (size_t)(obase + ot*16 + lr)*CC;
    #pragma unroll
    for (int ks = 0; ks < 8; ++ks) {
      float4 lo = *(const float4*)(wr + ks*32 + lg*8);
      float4 hi = *(const float4*)(wr + ks*32 + lg*8 + 4);
      afrag[ot][ks] = packAB(lo, hi);
    }
  }

  f32x4 macc = {0.f,0.f,0.f,0.f};     // M[head w] accumulated across tiles
  float zacc = 0.f;
  const float* xb = x + (size_t)b*CC*NN;
  short* PHI = xnt;                    // [64 d][PSTR]
  short* VV  = xnt + 64*PSTR;          // [64 e][PSTR]

  for (int t = 0; t < 4; ++t) {
    const int n0 = chunk*256 + t*64;
    __syncthreads();                   // prior M-MFMA reads done before overwrite
    stage_tile(xb, alds, blds, xnt, tid, n0);
    __syncthreads();

    // kv GEMM: D[o][n], o = obase+ot*16+row, n = nt*16+col
    f32x4 acc[2][4];
    #pragma unroll
    for (int ot=0;ot<2;++ot)
      #pragma unroll
      for (int nt=0;nt<4;++nt) acc[ot][nt] = (f32x4){0.f,0.f,0.f,0.f};
    #pragma unroll
    for (int ks = 0; ks < 8; ++ks) {
      bf16x8 bfr[4];
      #pragma unroll
      for (int nt = 0; nt < 4; ++nt)
        bfr[nt] = *(const bf16x8*)&xnt[(nt*16+lr)*XSTR + ks*32 + lg*8];
      #pragma unroll
      for (int ot = 0; ot < 2; ++ot)
        #pragma unroll
        for (int nt = 0; nt < 4; ++nt)
          acc[ot][nt] = MFMA16(afrag[ot][ks], bfr[nt], acc[ot][nt]);
    }
    __syncthreads();                   // xnt consumed
    // write phi_k (waves 0,1) / v (waves 2,3) as [row][n] bf16
    {
      short* dst = (w < 2) ? PHI : VV;
      #pragma unroll
      for (int ot = 0; ot < 2; ++ot)
        #pragma unroll
        for (int nt = 0; nt < 4; ++nt)
          #pragma unroll
          for (int r = 0; r < 4; ++r) {
            float v = acc[ot][nt][r];
            if (w < 2) v = elup1(v);
            dst[(obase + ot*16 + lg*4 + r)*PSTR + nt*16 + lr] = f2bf(v);
          }
    }
    __syncthreads();
    // M[head w][d][e] += sum_n phi_k[d][n] * v[e][n]  via MFMA (K = n, 2 steps)
    #pragma unroll
    for (int ks2 = 0; ks2 < 2; ++ks2) {
      bf16x8 af  = *(const bf16x8*)&PHI[(w*16+lr)*PSTR + ks2*32 + lg*8];
      bf16x8 bfv = *(const bf16x8*)&VV [(w*16+lr)*PSTR + ks2*32 + lg*8];
      macc = MFMA16(af, bfv, macc);
    }
    // Z[head w][d=lr] partial: lane sums its quarter of the row
    {
      const short* pr = &PHI[(w*16+lr)*PSTR + lg*16];
      #pragma unroll
      for (int j = 0; j < 16; ++j) zacc += bf2f(pr[j]);
    }
  }
  {
    float* mp = ws + WS_MPART + (size_t)(b*NCH + chunk)*1024 + w*256;
    #pragma unroll
    for (int r = 0; r < 4; ++r) mp[(lg*4+r)*16 + lr] = macc[r];  // D: col=lr, row=lg*4+r
    zacc += __shfl_xor(zacc, 16);
    zacc += __shfl_xor(zacc, 32);
    if (lg == 0) ws[WS_ZPART + (size_t)(b*NCH + chunk)*64 + w*16 + lr] = zacc;
  }
}

// ---------------- kernel 4: reduce partials, add M0/Z0 ----------------
__global__ __launch_bounds__(256) void k_reduce(const float* __restrict__ M0,
                                                const float* __restrict__ Z0,
                                                float* __restrict__ ws) {
  const int b = blockIdx.x, tid = threadIdx.x;
  const int idx0 = tid*4;
  float4 s = *(const float4*)(M0 + idx0);
  for (int ch = 0; ch < NCH; ++ch) {
    const float4 p = *(const float4*)&ws[WS_MPART + (size_t)(b*NCH + ch)*1024 + idx0];
    s.x += p.x; s.y += p.y; s.z += p.z; s.w += p.w;
  }
  *(float4*)&ws[WS_MF + b*1024 + idx0] = s;
  if (tid < 64) {
    float z = Z0[tid];
    for (int ch = 0; ch < NCH; ++ch)
      z += ws[WS_ZPART + (size_t)(b*NCH + ch)*64 + tid];
    ws[WS_ZF + b*64 + tid] = z;
  }
}

// ---------------- kernel 5: q proj + retrieval + out conv + residual (MFMA) ----------------
__global__ __launch_bounds__(256) void k_out(const float* __restrict__ x,
                                             const float* __restrict__ Wq,
                                             const float* __restrict__ Wout,
                                             const float* __restrict__ bout,
                                             const float* __restrict__ ws,
                                             float* __restrict__ out) {
  const int chunk = blockIdx.x, b = blockIdx.y;
  const int tid = threadIdx.x;
  const int w = tid >> 6, l = tid & 63, lr = l & 15, lg = l >> 4;
  __shared__ __align__(16) short xnt[64*XSTR];   // reused as ylds after q-GEMM
  __shared__ __align__(16) float Ml[1024];
  __shared__ float Zl[64];
  __shared__ float alds[CC], blds[CC];
  alds[tid] = ws[WS_AB + (b*CC+tid)*2];
  blds[tid] = ws[WS_AB + (b*CC+tid)*2 + 1];
  {
    const float* mf = ws + WS_MF + b*1024;
    *(float4*)&Ml[tid*4] = *(const float4*)&mf[tid*4];
    if (tid < 64) Zl[tid] = ws[WS_ZF + b*64 + tid];
  }
  const float gate = ws[WS_GATE + b];

  // Wq A-frags: wave w = head w (q rows w*16 .. +15)
  bf16x8 aq[8];
  {
    const float* wr = Wq + (size_t)(w*16 + lr)*CC;
    #pragma unroll
    for (int ks = 0; ks < 8; ++ks) {
      float4 lo = *(const float4*)(wr + ks*32 + lg*8);
      float4 hi = *(const float4*)(wr + ks*32 + lg*8 + 4);
      aq[ks] = packAB(lo, hi);
    }
  }
  // Wout A-frags: wave w -> out rows w*64 .. +63 (4 o-tiles), K=64 (2 steps)
  bf16x8 ao[4][2];
  float bo[4][4];
  #pragma unroll
  for (int oc = 0; oc < 4; ++oc) {
    const float* wr = Wout + (size_t)(w*64 + oc*16 + lr)*64;
    #pragma unroll
    for (int ks = 0; ks < 2; ++ks) {
      float4 lo = *(const float4*)(wr + ks*32 + lg*8);
      float4 hi = *(const float4*)(wr + ks*32 + lg*8 + 4);
      ao[oc][ks] = packAB(lo, hi);
    }
    #pragma unroll
    for (int r = 0; r < 4; ++r) bo[oc][r] = bout[w*64 + oc*16 + lg*4 + r];
  }

  short* ylds = xnt;   // [64 n][YSTR m]
  const float* xb = x + (size_t)b*CC*NN;

  for (int t = 0; t < 4; ++t) {
    const int n0 = chunk*256 + t*64;
    __syncthreads();                   // conv reads of ylds done before overwrite
    stage_tile(xb, alds, blds, xnt, tid, n0);
    __syncthreads();

    // q GEMM: wave w = head w; qa[nt] holds phi_q rows d=w*16+lg*4+r, col n=nt*16+lr
    f32x4 qa[4];
    #pragma unroll
    for (int nt=0;nt<4;++nt) qa[nt] = (f32x4){0.f,0.f,0.f,0.f};
    #pragma unroll
    for (int ks = 0; ks < 8; ++ks) {
      #pragma unroll
      for (int nt = 0; nt < 4; ++nt) {
        bf16x8 bfr = *(const bf16x8*)&xnt[(nt*16+lr)*XSTR + ks*32 + lg*8];
        qa[nt] = MFMA16(aq[ks], bfr, qa[nt]);
      }
    }
    __syncthreads();                   // xnt consumed; ylds writes allowed

    // phi + retrieval (in-register, cross-group shfl reduce over the 16 d's)
    #pragma unroll
    for (int nt = 0; nt < 4; ++nt) {
      float ph[4];
      #pragma unroll
      for (int r = 0; r < 4; ++r) ph[r] = elup1(qa[nt][r]);
      float num[16];
      #pragma unroll
      for (int e = 0; e < 16; ++e) num[e] = 0.f;
      float dn = 0.f;
      #pragma unroll
      for (int r = 0; r < 4; ++r) {
        dn = fmaf(Zl[w*16 + lg*4 + r], ph[r], dn);
        const float* mrow = &Ml[w*256 + (lg*4+r)*16];
        #pragma unroll
        for (int e = 0; e < 16; ++e) num[e] = fmaf(mrow[e], ph[r], num[e]);
      }
      #pragma unroll
      for (int e = 0; e < 16; ++e) {
        num[e] += __shfl_xor(num[e], 16);
        num[e] += __shfl_xor(num[e], 32);
      }
      dn += __shfl_xor(dn, 16);
      dn += __shfl_xor(dn, 32);
      dn = fmaxf(dn, 1e-4f);
      const float inv = 1.0f / dn;
      if (lg == nt) {                  // one group per n-tile writes (all identical)
        #pragma unroll
        for (int e4 = 0; e4 < 4; ++e4) {
          short4 s;
          s.x = f2bf(num[e4*4+0]*inv);
          s.y = f2bf(num[e4*4+1]*inv);
          s.z = f2bf(num[e4*4+2]*inv);
          s.w = f2bf(num[e4*4+3]*inv);
          *(short4*)&ylds[(nt*16+lr)*YSTR + w*16 + e4*4] = s;
        }
      }
    }
    __syncthreads();

    // out conv: D[o][n] = sum_m Wout[o][m] y[m][n]
    f32x4 co[4][4];
    #pragma unroll
    for (int oc=0;oc<4;++oc)
      #pragma unroll
      for (int nt=0;nt<4;++nt) co[oc][nt] = (f32x4){0.f,0.f,0.f,0.f};
    #pragma unroll
    for (int ks = 0; ks < 2; ++ks) {
      bf16x8 yb[4];
      #pragma unroll
      for (int nt = 0; nt < 4; ++nt)
        yb[nt] = *(const bf16x8*)&ylds[(nt*16+lr)*YSTR + ks*32 + lg*8];
      #pragma unroll
      for (int oc = 0; oc < 4; ++oc)
        #pragma unroll
        for (int nt = 0; nt < 4; ++nt)
          co[oc][nt] = MFMA16(ao[oc][ks], yb[nt], co[oc][nt]);
    }
    // epilogue: out = x + gate*(conv + bout)
    #pragma unroll
    for (int oc = 0; oc < 4; ++oc) {
      #pragma unroll
      for (int r = 0; r < 4; ++r) {
        const int o = w*64 + oc*16 + lg*4 + r;
        const size_t base = (size_t)(b*CC + o)*NN + n0 + lr;
        #pragma unroll
        for (int nt = 0; nt < 4; ++nt) {
          const size_t idx = base + nt*16;
          out[idx] = fmaf(gate, co[oc][nt][r] + bo[oc][r], x[idx]);
        }
      }
    }
  }
}

extern "C" void kernel_launch(void* const* d_in, const int* in_sizes, int n_in,
                              void* d_out, int out_size, void* d_ws, size_t ws_size,
                              hipStream_t stream) {
  (void)in_sizes; (void)n_in; (void)out_size; (void)ws_size;
  const float* x      = (const float*)d_in[0];
  const float* norm_w = (const float*)d_in[1];
  const float* norm_b = (const float*)d_in[2];
  const float* Wk     = (const float*)d_in[3];
  const float* Wv     = (const float*)d_in[4];
  const float* Wq     = (const float*)d_in[5];
  const float* Wout   = (const float*)d_in[6];
  const float* bout   = (const float*)d_in[7];
  const float* M0     = (const float*)d_in[8];
  const float* Z0     = (const float*)d_in[9];
  const float* Wg1    = (const float*)d_in[10];
  const float* bg1    = (const float*)d_in[11];
  const float* Wg2    = (const float*)d_in[12];
  const float* bg2    = (const float*)d_in[13];
  float* out = (float*)d_out;
  float* ws  = (float*)d_ws;

  hipLaunchKernelGGL(k_stats,  dim3(BB*CC),   dim3(256), 0, stream, x, ws);
  hipLaunchKernelGGL(k_prep,   dim3(BB),      dim3(256), 0, stream,
                     norm_w, norm_b, Wg1, bg1, Wg2, bg2, ws, out);
  hipLaunchKernelGGL(k_kv,     dim3(NCH, BB), dim3(256), 0, stream, x, Wk, Wv, ws);
  hipLaunchKernelGGL(k_reduce, dim3(BB),      dim3(256), 0, stream, M0, Z0, ws);
  hipLaunchKernelGGL(k_out,    dim3(NCH, BB), dim3(256), 0, stream,
                     x, Wq, Wout, bout, ws, out);
}